// Round 1
// baseline (1547.211 us; speedup 1.0000x reference)
//
#include <hip/hip_runtime.h>

typedef float vf4 __attribute__((ext_vector_type(4)));

#define LL 1024
#define DD 64
#define OO 128
#define BBATCH 4096
#define NS 511          // scan sites per sweep
#define SITE_F 8192     // floats per site tensor (64*2*64)

// ---- async global->LDS, 16B per lane ----
__device__ __forceinline__ void gld_lds16(const float* g, float* l) {
  __builtin_amdgcn_global_load_lds(
      (const __attribute__((address_space(1))) unsigned int*)g,
      (__attribute__((address_space(3))) unsigned int*)l, 16, 0, 0);
}

// stage one 32KB site tensor (8192 floats) with 256 threads
__device__ __forceinline__ void stage32k(float* lds, const float* g, int tid) {
#pragma unroll
  for (int q = 0; q < 8; q++) {
    const int off = (q * 256 + tid) * 4;  // float index; 16B per lane
    gld_lds16(g + off, lds + off);
  }
}

// ---- one-shot transpose of right_rest: (site,l,p,r) -> (site,r,p,l) ----
__global__ __launch_bounds__(256) void wr_transpose(const float* __restrict__ src,
                                                    float* __restrict__ dst) {
  __shared__ float S[SITE_F];
  const int site = blockIdx.x;
  const float* s = src + site * SITE_F;
  float* d = dst + site * SITE_F;
  const int tid = threadIdx.x;
#pragma unroll
  for (int m = 0; m < 8; m++) {
    *(vf4*)&S[(m * 256 + tid) * 4] = *(const vf4*)&s[(m * 256 + tid) * 4];
  }
  __syncthreads();
#pragma unroll
  for (int q = 0; q < 8; q++) {
    const int f = tid * 32 + q * 4;           // dst linear index, 4 consecutive
    const int r = f >> 7, p = (f >> 6) & 1, l = f & 63;
    vf4 v;
    v[0] = S[(l + 0) * 128 + p * 64 + r];
    v[1] = S[(l + 1) * 128 + p * 64 + r];
    v[2] = S[(l + 2) * 128 + p * 64 + r];
    v[3] = S[(l + 3) * 128 + p * 64 + r];
    *(vf4*)&d[f] = v;
  }
}

// ---- sweep kernel: both directions, unified reduction-over-first-axis ----
// thread map: cch = tid&15 -> 4 out cols (c0=4*cch), bch = tid>>4 -> 2 rows (b0=2*bch)
__global__ __launch_bounds__(256) void sweep(const float* __restrict__ x,
                                             const float* __restrict__ left0,
                                             const float* __restrict__ leftW,
                                             const float* __restrict__ rightWT,
                                             const float* __restrict__ right_last,
                                             float* __restrict__ envL,
                                             float* __restrict__ envR) {
  __shared__ float Ab[2][SITE_F];       // 64 KB double-buffered site tensor
  __shared__ float envT[2][32][68];     // [buf][b][k], padded 64->68 (bank spread)
  const int dir = blockIdx.y;           // 0 = left, 1 = right
  const int bbase = blockIdx.x * 32;
  const int tid = threadIdx.x;
  const int cch = tid & 15, bch = tid >> 4;
  const int c0 = cch * 4, b0 = bch * 2;

  const float* W = dir ? rightWT : leftW;

  float o[2][4];
  // ---- init env (site phi index t0) ----
  {
    const int t0 = dir ? (LL - 1) : 0;
#pragma unroll
    for (int r2 = 0; r2 < 2; r2++) {
      const float xv = x[(bbase + b0 + r2) * LL + t0];
      const float ang = 1.57079632679489662f * xv;
      const float sv = __sinf(ang), cv = __cosf(ang);
#pragma unroll
      for (int c = 0; c < 4; c++) {
        float w0, w1;
        if (dir == 0) { w0 = left0[c0 + c]; w1 = left0[64 + c0 + c]; }
        else { w0 = right_last[(c0 + c) * 2]; w1 = right_last[(c0 + c) * 2 + 1]; }
        o[r2][c] = cv * w0 + sv * w1;
      }
    }
    float ss0 = 0.f, ss1 = 0.f;
#pragma unroll
    for (int c = 0; c < 4; c++) { ss0 += o[0][c] * o[0][c]; ss1 += o[1][c] * o[1][c]; }
#pragma unroll
    for (int m = 1; m < 16; m <<= 1) { ss0 += __shfl_xor(ss0, m); ss1 += __shfl_xor(ss1, m); }
    const float i0 = 1.f / (sqrtf(ss0) + 1e-8f), i1 = 1.f / (sqrtf(ss1) + 1e-8f);
    vf4 v0, v1;
#pragma unroll
    for (int c = 0; c < 4; c++) { v0[c] = o[0][c] * i0; v1[c] = o[1][c] * i1; }
    *(vf4*)&envT[0][b0][c0] = v0;
    *(vf4*)&envT[0][b0 + 1][c0] = v1;
  }

  stage32k(Ab[0], W + (dir ? (NS - 1) : 0) * SITE_F, tid);

  for (int i = 0; i < NS; i++) {
    __syncthreads();  // env[i&1] + Ab[i&1] ready; prev buffers free
    const int buf = i & 1;
    if (i + 1 < NS)
      stage32k(Ab[buf ^ 1], W + (dir ? (NS - 2 - i) : (i + 1)) * SITE_F, tid);

    const int t = dir ? (1022 - i) : (1 + i);
    const float xv0 = x[(bbase + b0) * LL + t];       // issued early, used late
    const float xv1 = x[(bbase + b0 + 1) * LL + t];

    float u0[2][4] = {{0.f,0.f,0.f,0.f},{0.f,0.f,0.f,0.f}};
    float u1[2][4] = {{0.f,0.f,0.f,0.f},{0.f,0.f,0.f,0.f}};
    const float* A = Ab[buf];
#pragma unroll
    for (int k = 0; k < 64; k += 4) {
      const vf4 e0 = *(const vf4*)&envT[buf][b0][k];
      const vf4 e1 = *(const vf4*)&envT[buf][b0 + 1][k];
#pragma unroll
      for (int kk = 0; kk < 4; kk++) {
        const vf4 a0 = *(const vf4*)&A[(k + kk) * 128 + c0];        // p = 0
        const vf4 a1 = *(const vf4*)&A[(k + kk) * 128 + 64 + c0];   // p = 1
#pragma unroll
        for (int c = 0; c < 4; c++) {
          u0[0][c] += e0[kk] * a0[c];
          u0[1][c] += e1[kk] * a0[c];
          u1[0][c] += e0[kk] * a1[c];
          u1[1][c] += e1[kk] * a1[c];
        }
      }
    }
    const float ang0 = 1.57079632679489662f * xv0;
    const float ang1 = 1.57079632679489662f * xv1;
    const float s0 = __sinf(ang0), cc0 = __cosf(ang0);
    const float s1 = __sinf(ang1), cc1 = __cosf(ang1);
#pragma unroll
    for (int c = 0; c < 4; c++) {
      o[0][c] = cc0 * u0[0][c] + s0 * u1[0][c];
      o[1][c] = cc1 * u0[1][c] + s1 * u1[1][c];
    }
    float ss0 = 0.f, ss1 = 0.f;
#pragma unroll
    for (int c = 0; c < 4; c++) { ss0 += o[0][c] * o[0][c]; ss1 += o[1][c] * o[1][c]; }
#pragma unroll
    for (int m = 1; m < 16; m <<= 1) { ss0 += __shfl_xor(ss0, m); ss1 += __shfl_xor(ss1, m); }
    const float i0 = 1.f / (sqrtf(ss0) + 1e-8f), i1 = 1.f / (sqrtf(ss1) + 1e-8f);
    vf4 v0, v1;
#pragma unroll
    for (int c = 0; c < 4; c++) { o[0][c] *= i0; o[1][c] *= i1; v0[c] = o[0][c]; v1[c] = o[1][c]; }
    *(vf4*)&envT[buf ^ 1][b0][c0] = v0;
    *(vf4*)&envT[buf ^ 1][b0 + 1][c0] = v1;
  }

  float* eo = dir ? envR : envL;   // [b][c] natural layout
  vf4 w0, w1;
#pragma unroll
  for (int c = 0; c < 4; c++) { w0[c] = o[0][c]; w1[c] = o[1][c]; }
  *(vf4*)&eo[(bbase + b0) * 64 + c0] = w0;
  *(vf4*)&eo[(bbase + b0 + 1) * 64 + c0] = w1;
}

// ---- center contraction: out_part[b][o] = sum_{l in half, r} L[b,l] R[b,r] C[l,r,o] ----
// thread map: och = tid&31 -> 4 o cols, bch = tid>>5 -> 4 b rows
__global__ __launch_bounds__(256) void centerk(const float* __restrict__ envL,
                                               const float* __restrict__ envR,
                                               const float* __restrict__ center,
                                               float* __restrict__ Pp) {
  __shared__ float Cs[2][SITE_F];   // 64 KB, one l-slab (64 r x 128 o)
  __shared__ float LT[64 * 36];     // [l][b] padded 32->36
  __shared__ float RT[64 * 36];
  const int bbase = blockIdx.x * 32;
  const int half = blockIdx.y;
  const int tid = threadIdx.x;
  const int och = tid & 31, bch = tid >> 5;
  const int o0 = och * 4, b0 = bch * 4;
#pragma unroll
  for (int m = 0; m < 8; m++) {
    const int idx = m * 256 + tid;
    const int b = idx >> 6, l = idx & 63;
    LT[l * 36 + b] = envL[(bbase + b) * 64 + l];
    RT[l * 36 + b] = envR[(bbase + b) * 64 + l];
  }
  stage32k(Cs[0], center + (half * 32) * SITE_F, tid);
  float acc[4][4] = {};
  for (int lh = 0; lh < 32; lh++) {
    __syncthreads();
    const int buf = lh & 1;
    if (lh + 1 < 32) stage32k(Cs[buf ^ 1], center + (half * 32 + lh + 1) * SITE_F, tid);
    const vf4 lv = *(const vf4*)&LT[(half * 32 + lh) * 36 + b0];
    const float* C = Cs[buf];
#pragma unroll
    for (int r = 0; r < 64; r++) {
      const vf4 rv = *(const vf4*)&RT[r * 36 + b0];
      const vf4 cv = *(const vf4*)&C[r * 128 + o0];
#pragma unroll
      for (int i2 = 0; i2 < 4; i2++) {
        const float w = lv[i2] * rv[i2];
        acc[i2][0] += w * cv[0];
        acc[i2][1] += w * cv[1];
        acc[i2][2] += w * cv[2];
        acc[i2][3] += w * cv[3];
      }
    }
  }
#pragma unroll
  for (int i2 = 0; i2 < 4; i2++) {
    vf4 v; v[0] = acc[i2][0]; v[1] = acc[i2][1]; v[2] = acc[i2][2]; v[3] = acc[i2][3];
    *(vf4*)&Pp[(size_t)half * BBATCH * 128 + (size_t)(bbase + b0 + i2) * 128 + o0] = v;
  }
}

// ---- combine halves + row-normalize ----
__global__ __launch_bounds__(256) void combinek(const float* __restrict__ P,
                                                float* __restrict__ out) {
  const float* P0 = P;
  const float* P1 = P + (size_t)BBATCH * 128;
  const int row = blockIdx.x * 8 + (threadIdx.x >> 5);
  const int o0 = (threadIdx.x & 31) * 4;
  vf4 v = *(const vf4*)&P0[(size_t)row * 128 + o0];
  const vf4 v1 = *(const vf4*)&P1[(size_t)row * 128 + o0];
  v += v1;
  float ss = v[0] * v[0] + v[1] * v[1] + v[2] * v[2] + v[3] * v[3];
#pragma unroll
  for (int m = 1; m < 32; m <<= 1) ss += __shfl_xor(ss, m);
  const float inv = 1.f / fmaxf(sqrtf(ss), 1e-12f);
  v *= inv;
  *(vf4*)&out[(size_t)row * 128 + o0] = v;
}

extern "C" void kernel_launch(void* const* d_in, const int* in_sizes, int n_in,
                              void* d_out, int out_size, void* d_ws, size_t ws_size,
                              hipStream_t stream) {
  const float* x = (const float*)d_in[0];
  const float* left0 = (const float*)d_in[1];
  const float* left_rest = (const float*)d_in[2];
  const float* center = (const float*)d_in[3];
  const float* right_rest = (const float*)d_in[4];
  const float* right_last = (const float*)d_in[5];
  float* out = (float*)d_out;

  float* ws = (float*)d_ws;
  float* wrT = ws;                          // 511*8192 floats = 16.7 MB
  float* envL = wrT + (size_t)NS * SITE_F;  // 4096*64
  float* envR = envL + (size_t)BBATCH * 64;
  float* Pp = envR + (size_t)BBATCH * 64;   // 2 * 4096*128

  hipLaunchKernelGGL(wr_transpose, dim3(NS), dim3(256), 0, stream, right_rest, wrT);
  hipLaunchKernelGGL(sweep, dim3(BBATCH / 32, 2), dim3(256), 0, stream,
                     x, left0, left_rest, wrT, right_last, envL, envR);
  hipLaunchKernelGGL(centerk, dim3(BBATCH / 32, 2), dim3(256), 0, stream,
                     envL, envR, center, Pp);
  hipLaunchKernelGGL(combinek, dim3(BBATCH / 8), dim3(256), 0, stream, Pp, out);
}

// Round 2
// 1451.523 us; speedup vs baseline: 1.0659x; 1.0659x over previous
//
#include <hip/hip_runtime.h>

typedef float vf4 __attribute__((ext_vector_type(4)));

#define LL 1024
#define DD 64
#define OO 128
#define BBATCH 4096
#define NS 511          // scan sites per sweep
#define SITE_F 8192     // floats per site tensor (64*2*64)

// ---- async global->LDS, 16B per lane ----
__device__ __forceinline__ void gld_lds16(const float* g, float* l) {
  __builtin_amdgcn_global_load_lds(
      (const __attribute__((address_space(1))) unsigned int*)g,
      (__attribute__((address_space(3))) unsigned int*)l, 16, 0, 0);
}

// stage one 32KB site tensor (8192 floats) with 512 threads
__device__ __forceinline__ void stage32k_512(float* lds, const float* g, int tid) {
#pragma unroll
  for (int q = 0; q < 4; q++) {
    const int off = (q * 512 + tid) * 4;  // float index; 16B per lane
    gld_lds16(g + off, lds + off);
  }
}

// stage one 32KB site tensor (8192 floats) with 256 threads
__device__ __forceinline__ void stage32k_256(float* lds, const float* g, int tid) {
#pragma unroll
  for (int q = 0; q < 8; q++) {
    const int off = (q * 256 + tid) * 4;
    gld_lds16(g + off, lds + off);
  }
}

// ---- one-shot transpose of right_rest: (site,l,p,r) -> (site,r,p,l) ----
__global__ __launch_bounds__(256) void wr_transpose(const float* __restrict__ src,
                                                    float* __restrict__ dst) {
  __shared__ float S[SITE_F];
  const int site = blockIdx.x;
  const float* s = src + site * SITE_F;
  float* d = dst + site * SITE_F;
  const int tid = threadIdx.x;
#pragma unroll
  for (int m = 0; m < 8; m++) {
    *(vf4*)&S[(m * 256 + tid) * 4] = *(const vf4*)&s[(m * 256 + tid) * 4];
  }
  __syncthreads();
#pragma unroll
  for (int q = 0; q < 8; q++) {
    const int f = tid * 32 + q * 4;           // dst linear index, 4 consecutive
    const int r = f >> 7, p = (f >> 6) & 1, l = f & 63;
    vf4 v;
    v[0] = S[(l + 0) * 128 + p * 64 + r];
    v[1] = S[(l + 1) * 128 + p * 64 + r];
    v[2] = S[(l + 2) * 128 + p * 64 + r];
    v[3] = S[(l + 3) * 128 + p * 64 + r];
    *(vf4*)&d[f] = v;
  }
}

// ---- sweep kernel: 512 threads, 32 batch rows, k-split across wave pairs ----
// wave = tid>>6; ksel = wave&1 (k-half); wgrp = wave>>1
// lane: cch = lane&15 -> 4 cols (c0=4*cch); bch = lane>>4; b0 = (wgrp*4+bch)*2 -> 2 rows
__global__ __launch_bounds__(512) void sweep(const float* __restrict__ x,
                                             const float* __restrict__ left0,
                                             const float* __restrict__ leftW,
                                             const float* __restrict__ rightWT,
                                             const float* __restrict__ right_last,
                                             float* __restrict__ envL,
                                             float* __restrict__ envR) {
  __shared__ float Ab[2][SITE_F];       // 64 KB double-buffered site tensor
  __shared__ float envT[2][32][68];     // [buf][b][k], padded 64->68
  __shared__ float Scr[32][68];         // k-half partial exchange
  const int dir = blockIdx.y;           // 0 = left, 1 = right
  const int bbase = blockIdx.x * 32;
  const int tid = threadIdx.x;
  const int lane = tid & 63;
  const int wave = tid >> 6;
  const int ksel = wave & 1;
  const int wgrp = wave >> 1;
  const int cch = lane & 15, bch = lane >> 4;
  const int c0 = cch * 4;
  const int b0 = (wgrp * 4 + bch) * 2;
  const int k0 = ksel * 32;

  const float* W = dir ? rightWT : leftW;

  stage32k_512(Ab[0], W + (dir ? (NS - 1) : 0) * SITE_F, tid);

  // ---- init env (site phi index t0); all waves compute, ksel==0 writes ----
  {
    const int t0 = dir ? (LL - 1) : 0;
    float o[2][4];
#pragma unroll
    for (int r2 = 0; r2 < 2; r2++) {
      const float xv = x[(bbase + b0 + r2) * LL + t0];
      const float ang = 1.57079632679489662f * xv;
      const float sv = __sinf(ang), cv = __cosf(ang);
#pragma unroll
      for (int c = 0; c < 4; c++) {
        float w0, w1;
        if (dir == 0) { w0 = left0[c0 + c]; w1 = left0[64 + c0 + c]; }
        else { w0 = right_last[(c0 + c) * 2]; w1 = right_last[(c0 + c) * 2 + 1]; }
        o[r2][c] = cv * w0 + sv * w1;
      }
    }
    float ss0 = 0.f, ss1 = 0.f;
#pragma unroll
    for (int c = 0; c < 4; c++) { ss0 += o[0][c] * o[0][c]; ss1 += o[1][c] * o[1][c]; }
#pragma unroll
    for (int m = 1; m < 16; m <<= 1) { ss0 += __shfl_xor(ss0, m); ss1 += __shfl_xor(ss1, m); }
    const float i0 = 1.f / (sqrtf(ss0) + 1e-8f), i1 = 1.f / (sqrtf(ss1) + 1e-8f);
    if (ksel == 0) {
      vf4 v0, v1;
#pragma unroll
      for (int c = 0; c < 4; c++) { v0[c] = o[0][c] * i0; v1[c] = o[1][c] * i1; }
      *(vf4*)&envT[0][b0][c0] = v0;
      *(vf4*)&envT[0][b0 + 1][c0] = v1;
    }
  }
  __syncthreads();   // envT[0] ready; Ab[0] staged (vmcnt drained at barrier)

  float o[2][4];     // final env lives here on ksel==0 waves
  for (int i = 0; i < NS; i++) {
    const int buf = i & 1;
    if (i + 1 < NS)
      stage32k_512(Ab[buf ^ 1], W + (dir ? (NS - 2 - i) : (i + 1)) * SITE_F, tid);

    const int t = dir ? (1022 - i) : (1 + i);
    const float xv0 = x[(bbase + b0) * LL + t];       // issued early, used late
    const float xv1 = x[(bbase + b0 + 1) * LL + t];

    float u0[2][4] = {{0.f,0.f,0.f,0.f},{0.f,0.f,0.f,0.f}};
    float u1[2][4] = {{0.f,0.f,0.f,0.f},{0.f,0.f,0.f,0.f}};
    const float* A = Ab[buf];
#pragma unroll
    for (int j = 0; j < 8; j++) {
      const int k = k0 + j * 4;
      const vf4 e0 = *(const vf4*)&envT[buf][b0][k];
      const vf4 e1 = *(const vf4*)&envT[buf][b0 + 1][k];
#pragma unroll
      for (int kk = 0; kk < 4; kk++) {
        const vf4 a0 = *(const vf4*)&A[(k + kk) * 128 + c0];        // p = 0
        const vf4 a1 = *(const vf4*)&A[(k + kk) * 128 + 64 + c0];   // p = 1
#pragma unroll
        for (int c = 0; c < 4; c++) {
          u0[0][c] += e0[kk] * a0[c];
          u0[1][c] += e1[kk] * a0[c];
          u1[0][c] += e0[kk] * a1[c];
          u1[1][c] += e1[kk] * a1[c];
        }
      }
    }
    const float ang0 = 1.57079632679489662f * xv0;
    const float ang1 = 1.57079632679489662f * xv1;
    const float s0 = __sinf(ang0), cc0 = __cosf(ang0);
    const float s1 = __sinf(ang1), cc1 = __cosf(ang1);
    float op[2][4];
#pragma unroll
    for (int c = 0; c < 4; c++) {
      op[0][c] = cc0 * u0[0][c] + s0 * u1[0][c];
      op[1][c] = cc1 * u0[1][c] + s1 * u1[1][c];
    }
    if (ksel) {   // wave-uniform branch
      vf4 w0, w1;
#pragma unroll
      for (int c = 0; c < 4; c++) { w0[c] = op[0][c]; w1[c] = op[1][c]; }
      *(vf4*)&Scr[b0][c0] = w0;
      *(vf4*)&Scr[b0 + 1][c0] = w1;
    }
    __syncthreads();   // Scr ready
    if (!ksel) {
      const vf4 p0 = *(const vf4*)&Scr[b0][c0];
      const vf4 p1 = *(const vf4*)&Scr[b0 + 1][c0];
#pragma unroll
      for (int c = 0; c < 4; c++) { o[0][c] = op[0][c] + p0[c]; o[1][c] = op[1][c] + p1[c]; }
      float ss0 = 0.f, ss1 = 0.f;
#pragma unroll
      for (int c = 0; c < 4; c++) { ss0 += o[0][c] * o[0][c]; ss1 += o[1][c] * o[1][c]; }
#pragma unroll
      for (int m = 1; m < 16; m <<= 1) { ss0 += __shfl_xor(ss0, m); ss1 += __shfl_xor(ss1, m); }
      const float i0 = 1.f / (sqrtf(ss0) + 1e-8f), i1 = 1.f / (sqrtf(ss1) + 1e-8f);
      vf4 v0, v1;
#pragma unroll
      for (int c = 0; c < 4; c++) { o[0][c] *= i0; o[1][c] *= i1; v0[c] = o[0][c]; v1[c] = o[1][c]; }
      *(vf4*)&envT[buf ^ 1][b0][c0] = v0;
      *(vf4*)&envT[buf ^ 1][b0 + 1][c0] = v1;
    }
    __syncthreads();   // envT[buf^1] ready; Ab[buf] fully consumed
  }

  if (!ksel) {
    float* eo = dir ? envR : envL;   // [b][c] natural layout
    vf4 w0, w1;
#pragma unroll
    for (int c = 0; c < 4; c++) { w0[c] = o[0][c]; w1[c] = o[1][c]; }
    *(vf4*)&eo[(bbase + b0) * 64 + c0] = w0;
    *(vf4*)&eo[(bbase + b0 + 1) * 64 + c0] = w1;
  }
}

// ---- center contraction: out_part[b][o] = sum_{l in half, r} L[b,l] R[b,r] C[l,r,o] ----
// thread map: och = tid&31 -> 4 o cols, bch = tid>>5 -> 4 b rows
__global__ __launch_bounds__(256) void centerk(const float* __restrict__ envL,
                                               const float* __restrict__ envR,
                                               const float* __restrict__ center,
                                               float* __restrict__ Pp) {
  __shared__ float Cs[2][SITE_F];   // 64 KB, one l-slab (64 r x 128 o)
  __shared__ float LT[64 * 36];     // [l][b] padded 32->36
  __shared__ float RT[64 * 36];
  const int bbase = blockIdx.x * 32;
  const int half = blockIdx.y;
  const int tid = threadIdx.x;
  const int och = tid & 31, bch = tid >> 5;
  const int o0 = och * 4, b0 = bch * 4;
#pragma unroll
  for (int m = 0; m < 8; m++) {
    const int idx = m * 256 + tid;
    const int b = idx >> 6, l = idx & 63;
    LT[l * 36 + b] = envL[(bbase + b) * 64 + l];
    RT[l * 36 + b] = envR[(bbase + b) * 64 + l];
  }
  stage32k_256(Cs[0], center + (half * 32) * SITE_F, tid);
  float acc[4][4] = {};
  for (int lh = 0; lh < 32; lh++) {
    __syncthreads();
    const int buf = lh & 1;
    if (lh + 1 < 32) stage32k_256(Cs[buf ^ 1], center + (half * 32 + lh + 1) * SITE_F, tid);
    const vf4 lv = *(const vf4*)&LT[(half * 32 + lh) * 36 + b0];
    const float* C = Cs[buf];
#pragma unroll
    for (int r = 0; r < 64; r++) {
      const vf4 rv = *(const vf4*)&RT[r * 36 + b0];
      const vf4 cv = *(const vf4*)&C[r * 128 + o0];
#pragma unroll
      for (int i2 = 0; i2 < 4; i2++) {
        const float w = lv[i2] * rv[i2];
        acc[i2][0] += w * cv[0];
        acc[i2][1] += w * cv[1];
        acc[i2][2] += w * cv[2];
        acc[i2][3] += w * cv[3];
      }
    }
  }
#pragma unroll
  for (int i2 = 0; i2 < 4; i2++) {
    vf4 v; v[0] = acc[i2][0]; v[1] = acc[i2][1]; v[2] = acc[i2][2]; v[3] = acc[i2][3];
    *(vf4*)&Pp[(size_t)half * BBATCH * 128 + (size_t)(bbase + b0 + i2) * 128 + o0] = v;
  }
}

// ---- combine halves + row-normalize ----
__global__ __launch_bounds__(256) void combinek(const float* __restrict__ P,
                                                float* __restrict__ out) {
  const float* P0 = P;
  const float* P1 = P + (size_t)BBATCH * 128;
  const int row = blockIdx.x * 8 + (threadIdx.x >> 5);
  const int o0 = (threadIdx.x & 31) * 4;
  vf4 v = *(const vf4*)&P0[(size_t)row * 128 + o0];
  const vf4 v1 = *(const vf4*)&P1[(size_t)row * 128 + o0];
  v += v1;
  float ss = v[0] * v[0] + v[1] * v[1] + v[2] * v[2] + v[3] * v[3];
#pragma unroll
  for (int m = 1; m < 32; m <<= 1) ss += __shfl_xor(ss, m);
  const float inv = 1.f / fmaxf(sqrtf(ss), 1e-12f);
  v *= inv;
  *(vf4*)&out[(size_t)row * 128 + o0] = v;
}

extern "C" void kernel_launch(void* const* d_in, const int* in_sizes, int n_in,
                              void* d_out, int out_size, void* d_ws, size_t ws_size,
                              hipStream_t stream) {
  const float* x = (const float*)d_in[0];
  const float* left0 = (const float*)d_in[1];
  const float* left_rest = (const float*)d_in[2];
  const float* center = (const float*)d_in[3];
  const float* right_rest = (const float*)d_in[4];
  const float* right_last = (const float*)d_in[5];
  float* out = (float*)d_out;

  float* ws = (float*)d_ws;
  float* wrT = ws;                          // 511*8192 floats = 16.7 MB
  float* envL = wrT + (size_t)NS * SITE_F;  // 4096*64
  float* envR = envL + (size_t)BBATCH * 64;
  float* Pp = envR + (size_t)BBATCH * 64;   // 2 * 4096*128

  hipLaunchKernelGGL(wr_transpose, dim3(NS), dim3(256), 0, stream, right_rest, wrT);
  hipLaunchKernelGGL(sweep, dim3(BBATCH / 32, 2), dim3(512), 0, stream,
                     x, left0, left_rest, wrT, right_last, envL, envR);
  hipLaunchKernelGGL(centerk, dim3(BBATCH / 32, 2), dim3(256), 0, stream,
                     envL, envR, center, Pp);
  hipLaunchKernelGGL(combinek, dim3(BBATCH / 8), dim3(256), 0, stream, Pp, out);
}

// Round 3
// 653.669 us; speedup vs baseline: 2.3670x; 2.2206x over previous
//
#include <hip/hip_runtime.h>

typedef float vf4 __attribute__((ext_vector_type(4)));
typedef short short8 __attribute__((ext_vector_type(8)));
typedef unsigned short ushort8 __attribute__((ext_vector_type(8)));
typedef float f32x16 __attribute__((ext_vector_type(16)));

#define LL 1024
#define DD 64
#define OO 128
#define BBATCH 4096
#define NS 511          // scan sites per sweep
#define SITE_F 8192     // elements per site tensor (64*2*64)

// ---- async global->LDS ----
__device__ __forceinline__ void gld_lds16(const float* g, float* l) {
  __builtin_amdgcn_global_load_lds(
      (const __attribute__((address_space(1))) unsigned int*)g,
      (__attribute__((address_space(3))) unsigned int*)l, 16, 0, 0);
}

__device__ __forceinline__ void stage32k_256(float* lds, const float* g, int tid) {
#pragma unroll
  for (int q = 0; q < 8; q++) {
    const int off = (q * 256 + tid) * 4;
    gld_lds16(g + off, lds + off);
  }
}

// ---- one-shot: build bf16 fragment-major N = A - I for both sweeps ----
// layout: W[site][sm][lane][j] bf16, sm = s*2+mt (s=K-step 0..7, mt=M-tile 0..1)
// element = N[k2][n], k2 = 16s + 8*(lane>>5) + j, n = 32*mt + (lane&31)
// right buffer is site-reversed so the sweep always walks ascending.
__global__ __launch_bounds__(256) void prep(const float* __restrict__ lsrc,
                                            const float* __restrict__ rsrc,
                                            unsigned short* __restrict__ Wl,
                                            unsigned short* __restrict__ Wr) {
  __shared__ float S[SITE_F];
  const int site = blockIdx.x;
  const int dir = blockIdx.y;
  const int tid = threadIdx.x;
  const float* src = (dir ? rsrc : lsrc) + (size_t)site * SITE_F;
  unsigned short* dst = dir ? (Wr + (size_t)(NS - 1 - site) * SITE_F)
                            : (Wl + (size_t)site * SITE_F);
#pragma unroll
  for (int m = 0; m < 8; m++)
    *(vf4*)&S[(m * 256 + tid) * 4] = *(const vf4*)&src[(m * 256 + tid) * 4];
  __syncthreads();
#pragma unroll
  for (int q = 0; q < 4; q++) {
    const int slot = q * 256 + tid;           // 0..1023 = sm*64 + lane
    const int lane = slot & 63, sm = slot >> 6;
    const int s = sm >> 1, mt = sm & 1;
    const int hi = lane >> 5, ln = lane & 31;
    const int n = 32 * mt + ln;
    ushort8 t;
#pragma unroll
    for (int j = 0; j < 8; j++) {
      const int k2 = 16 * s + 8 * hi + j;
      float v;
      if (dir == 0) {
        // left: N[(l,p)][r] = A[l][p][r] - delta_{l,r};  l = k2>>1
        v = S[k2 * 64 + n] - ((n == (k2 >> 1)) ? 1.f : 0.f);
      } else {
        // right: N[(r,p)][l] = A[l][p][r] - delta_{l,r}
        const int r = k2 >> 1, p = k2 & 1;
        v = S[n * 128 + p * 64 + r] - ((n == r) ? 1.f : 0.f);
      }
      const unsigned uu = __builtin_bit_cast(unsigned, v);
      t[j] = (unsigned short)((uu + 0x7FFFu + ((uu >> 16) & 1u)) >> 16);  // RNE
    }
    *(ushort8*)&dst[(size_t)slot * 8] = t;
  }
}

// ---- sweep: 1 wave = 32 batch rows, full 511-site chain, lane-local ----
// env' = (cos+sin)*env + (env (x) phi) * N   via mfma_f32_32x32x16_bf16
// u unnormalized; alpha = 1/||u|| folded into the scalars each step.
__global__ __launch_bounds__(64) void sweep(const float* __restrict__ x,
                                            const float* __restrict__ left0,
                                            const float* __restrict__ right_last,
                                            const unsigned short* __restrict__ Wl,
                                            const unsigned short* __restrict__ Wr,
                                            float* __restrict__ envL,
                                            float* __restrict__ envR) {
  __shared__ float wf[2][4096];           // 2 x 16KB bf16 site frags
  const int bid = blockIdx.x;
  const int dir = bid >> 7;
  const int lane = threadIdx.x;
  const int hi = lane >> 5, ln = lane & 31;
  const int b = (bid & 127) * 32 + ln;

  const float* W = (const float*)(dir ? Wr : Wl);

  // prestage site 0 (16 vmem ops)
#pragma unroll
  for (int q = 0; q < 16; q++)
    gld_lds16(W + (q * 64 + lane) * 4, &wf[0][(q * 64 + lane) * 4]);

  // init env from boundary tensor (fp32, raw weights)
  float u[2][16];
  {
    const float x0 = x[(size_t)b * LL + (dir ? (LL - 1) : 0)];
    const float ang = 1.57079632679489662f * x0;
    const float sn = __sinf(ang), cs = __cosf(ang);
#pragma unroll
    for (int mt = 0; mt < 2; mt++)
#pragma unroll
      for (int r = 0; r < 16; r++) {
        const int n = 32 * mt + 8 * (r >> 2) + 4 * hi + (r & 3);
        const float w0 = dir ? right_last[n * 2] : left0[n];
        const float w1 = dir ? right_last[n * 2 + 1] : left0[64 + n];
        u[mt][r] = cs * w0 + sn * w1;
      }
  }
  float ss = 0.f;
#pragma unroll
  for (int mt = 0; mt < 2; mt++)
#pragma unroll
    for (int r = 0; r < 16; r++) ss += u[mt][r] * u[mt][r];
  ss += __shfl_xor(ss, 32);
  float alpha = 1.f / (sqrtf(ss) + 1e-8f);

  float xc = x[(size_t)b * LL + (dir ? 1022 : 1)];   // x for site 0 (1 vmem)

  for (int i = 0; i < NS; i++) {
    const int cur = i & 1;
    float xn = 0.f;
    if (i + 1 < NS) {
      const float* Wn = W + (size_t)(i + 1) * 4096;
      float* dstb = &wf[cur ^ 1][0];
#pragma unroll
      for (int q = 0; q < 16; q++)
        gld_lds16(Wn + (q * 64 + lane) * 4, dstb + (q * 64 + lane) * 4);
      xn = x[(size_t)b * LL + (dir ? (1021 - i) : (2 + i))];
      // 17 newest (next stage + xn) may stay in flight; drain cur stage + xc
      asm volatile("s_waitcnt vmcnt(17)" ::: "memory");
    } else {
      asm volatile("s_waitcnt vmcnt(0)" ::: "memory");
    }

    const float ang = 1.57079632679489662f * xc;
    const float sn = __sinf(ang), cs = __cosf(ang);
    const float ca = cs * alpha, sa = sn * alpha;
    const float keff = (cs + sn) * alpha;

    // B-frags: e2[s][j] = u-value(c = 8s+4hi+(j>>1)) * (alpha*phi[j&1]), bf16
    short8 e2[8];
#pragma unroll
    for (int s = 0; s < 8; s++) {
      int pk[4];
#pragma unroll
      for (int t = 0; t < 4; t++) {
        const float uv = u[s >> 2][(s & 3) * 4 + t];
        const float f0 = uv * ca, f1 = uv * sa;
        int p;
        asm("v_cvt_pk_bf16_f32 %0, %1, %2" : "=v"(p) : "v"(f0), "v"(f1));
        pk[t] = p;
      }
      short8 e;
#pragma unroll
      for (int t = 0; t < 4; t++) {
        e[2 * t] = (short)(pk[t] & 0xFFFF);
        e[2 * t + 1] = (short)((unsigned)pk[t] >> 16);
      }
      e2[s] = e;
    }

    // MFMA: acc[mt] += A(W-frag) * B(e2), 4 accumulators to break dep chains
    f32x16 acc0a = {}, acc0b = {}, acc1a = {}, acc1b = {};
    const float* wc = &wf[cur][0];
#pragma unroll
    for (int s = 0; s < 4; s++) {
      const short8 a0 = __builtin_bit_cast(short8, *(const vf4*)&wc[((s * 2 + 0) * 64 + lane) * 4]);
      const short8 a1 = __builtin_bit_cast(short8, *(const vf4*)&wc[((s * 2 + 1) * 64 + lane) * 4]);
      acc0a = __builtin_amdgcn_mfma_f32_32x32x16_bf16(a0, e2[s], acc0a, 0, 0, 0);
      acc1a = __builtin_amdgcn_mfma_f32_32x32x16_bf16(a1, e2[s], acc1a, 0, 0, 0);
    }
#pragma unroll
    for (int s = 4; s < 8; s++) {
      const short8 a0 = __builtin_bit_cast(short8, *(const vf4*)&wc[((s * 2 + 0) * 64 + lane) * 4]);
      const short8 a1 = __builtin_bit_cast(short8, *(const vf4*)&wc[((s * 2 + 1) * 64 + lane) * 4]);
      acc0b = __builtin_amdgcn_mfma_f32_32x32x16_bf16(a0, e2[s], acc0b, 0, 0, 0);
      acc1b = __builtin_amdgcn_mfma_f32_32x32x16_bf16(a1, e2[s], acc1b, 0, 0, 0);
    }

    // u' = keff*u + acc ; new norm
    float nss = 0.f;
#pragma unroll
    for (int r = 0; r < 16; r++) {
      const float u0 = keff * u[0][r] + (acc0a[r] + acc0b[r]);
      const float u1 = keff * u[1][r] + (acc1a[r] + acc1b[r]);
      u[0][r] = u0; u[1][r] = u1;
      nss += u0 * u0 + u1 * u1;
    }
    nss += __shfl_xor(nss, 32);
    alpha = 1.f / (sqrtf(nss) + 1e-8f);
    xc = xn;
  }

  // write normalized env, vectorized (n = 32mt + 8g + 4hi + q)
  float* eo = (dir ? envR : envL) + (size_t)b * 64;
#pragma unroll
  for (int mt = 0; mt < 2; mt++)
#pragma unroll
    for (int g = 0; g < 4; g++) {
      vf4 v;
#pragma unroll
      for (int q = 0; q < 4; q++) v[q] = u[mt][g * 4 + q] * alpha;
      *(vf4*)&eo[32 * mt + 8 * g + 4 * hi] = v;
    }
}

// ---- center contraction (unchanged, fp32) ----
__global__ __launch_bounds__(256) void centerk(const float* __restrict__ envL,
                                               const float* __restrict__ envR,
                                               const float* __restrict__ center,
                                               float* __restrict__ Pp) {
  __shared__ float Cs[2][SITE_F];
  __shared__ float LT[64 * 36];
  __shared__ float RT[64 * 36];
  const int bbase = blockIdx.x * 32;
  const int half = blockIdx.y;
  const int tid = threadIdx.x;
  const int och = tid & 31, bch = tid >> 5;
  const int o0 = och * 4, b0 = bch * 4;
#pragma unroll
  for (int m = 0; m < 8; m++) {
    const int idx = m * 256 + tid;
    const int b = idx >> 6, l = idx & 63;
    LT[l * 36 + b] = envL[(bbase + b) * 64 + l];
    RT[l * 36 + b] = envR[(bbase + b) * 64 + l];
  }
  stage32k_256(Cs[0], center + (half * 32) * SITE_F, tid);
  float acc[4][4] = {};
  for (int lh = 0; lh < 32; lh++) {
    __syncthreads();
    const int buf = lh & 1;
    if (lh + 1 < 32) stage32k_256(Cs[buf ^ 1], center + (half * 32 + lh + 1) * SITE_F, tid);
    const vf4 lv = *(const vf4*)&LT[(half * 32 + lh) * 36 + b0];
    const float* C = Cs[buf];
#pragma unroll
    for (int r = 0; r < 64; r++) {
      const vf4 rv = *(const vf4*)&RT[r * 36 + b0];
      const vf4 cv = *(const vf4*)&C[r * 128 + o0];
#pragma unroll
      for (int i2 = 0; i2 < 4; i2++) {
        const float w = lv[i2] * rv[i2];
        acc[i2][0] += w * cv[0];
        acc[i2][1] += w * cv[1];
        acc[i2][2] += w * cv[2];
        acc[i2][3] += w * cv[3];
      }
    }
  }
#pragma unroll
  for (int i2 = 0; i2 < 4; i2++) {
    vf4 v; v[0] = acc[i2][0]; v[1] = acc[i2][1]; v[2] = acc[i2][2]; v[3] = acc[i2][3];
    *(vf4*)&Pp[(size_t)half * BBATCH * 128 + (size_t)(bbase + b0 + i2) * 128 + o0] = v;
  }
}

// ---- combine halves + row-normalize ----
__global__ __launch_bounds__(256) void combinek(const float* __restrict__ P,
                                                float* __restrict__ out) {
  const float* P0 = P;
  const float* P1 = P + (size_t)BBATCH * 128;
  const int row = blockIdx.x * 8 + (threadIdx.x >> 5);
  const int o0 = (threadIdx.x & 31) * 4;
  vf4 v = *(const vf4*)&P0[(size_t)row * 128 + o0];
  const vf4 v1 = *(const vf4*)&P1[(size_t)row * 128 + o0];
  v += v1;
  float ss = v[0] * v[0] + v[1] * v[1] + v[2] * v[2] + v[3] * v[3];
#pragma unroll
  for (int m = 1; m < 32; m <<= 1) ss += __shfl_xor(ss, m);
  const float inv = 1.f / fmaxf(sqrtf(ss), 1e-12f);
  v *= inv;
  *(vf4*)&out[(size_t)row * 128 + o0] = v;
}

extern "C" void kernel_launch(void* const* d_in, const int* in_sizes, int n_in,
                              void* d_out, int out_size, void* d_ws, size_t ws_size,
                              hipStream_t stream) {
  const float* x = (const float*)d_in[0];
  const float* left0 = (const float*)d_in[1];
  const float* left_rest = (const float*)d_in[2];
  const float* center = (const float*)d_in[3];
  const float* right_rest = (const float*)d_in[4];
  const float* right_last = (const float*)d_in[5];
  float* out = (float*)d_out;

  char* wsb = (char*)d_ws;
  unsigned short* Wl = (unsigned short*)wsb;                       // 8.37 MB
  unsigned short* Wr = Wl + (size_t)NS * SITE_F;                   // 8.37 MB
  float* envL = (float*)(Wr + (size_t)NS * SITE_F);                // 1 MB
  float* envR = envL + (size_t)BBATCH * 64;                        // 1 MB
  float* Pp = envR + (size_t)BBATCH * 64;                          // 4.2 MB

  hipLaunchKernelGGL(prep, dim3(NS, 2), dim3(256), 0, stream,
                     left_rest, right_rest, Wl, Wr);
  hipLaunchKernelGGL(sweep, dim3(256), dim3(64), 0, stream,
                     x, left0, right_last, Wl, Wr, envL, envR);
  hipLaunchKernelGGL(centerk, dim3(BBATCH / 32, 2), dim3(256), 0, stream,
                     envL, envR, center, Pp);
  hipLaunchKernelGGL(combinek, dim3(BBATCH / 8), dim3(256), 0, stream, Pp, out);
}

// Round 4
// 496.170 us; speedup vs baseline: 3.1183x; 1.3174x over previous
//
#include <hip/hip_runtime.h>

typedef float vf4 __attribute__((ext_vector_type(4)));
typedef short short8 __attribute__((ext_vector_type(8)));
typedef unsigned short ushort8 __attribute__((ext_vector_type(8)));
typedef float f32x16 __attribute__((ext_vector_type(16)));

#define LL 1024
#define DD 64
#define OO 128
#define BBATCH 4096
#define NS 511          // scan sites per sweep
#define SITE_F 8192     // elements per site tensor (64*2*64)
#define PI_2 1.57079632679489662f

// ---- async global->LDS ----
__device__ __forceinline__ void gld_lds16(const float* g, float* l) {
  __builtin_amdgcn_global_load_lds(
      (const __attribute__((address_space(1))) unsigned int*)g,
      (__attribute__((address_space(3))) unsigned int*)l, 16, 0, 0);
}

__device__ __forceinline__ void stage32k_256(float* lds, const float* g, int tid) {
#pragma unroll
  for (int q = 0; q < 8; q++) {
    const int off = (q * 256 + tid) * 4;
    gld_lds16(g + off, lds + off);
  }
}

// ---- one-shot: build bf16 fragment-major N = A - I for both sweeps ----
__global__ __launch_bounds__(256) void prep(const float* __restrict__ lsrc,
                                            const float* __restrict__ rsrc,
                                            unsigned short* __restrict__ Wl,
                                            unsigned short* __restrict__ Wr) {
  __shared__ float S[SITE_F];
  const int site = blockIdx.x;
  const int dir = blockIdx.y;
  const int tid = threadIdx.x;
  const float* src = (dir ? rsrc : lsrc) + (size_t)site * SITE_F;
  unsigned short* dst = dir ? (Wr + (size_t)(NS - 1 - site) * SITE_F)
                            : (Wl + (size_t)site * SITE_F);
#pragma unroll
  for (int m = 0; m < 8; m++)
    *(vf4*)&S[(m * 256 + tid) * 4] = *(const vf4*)&src[(m * 256 + tid) * 4];
  __syncthreads();
#pragma unroll
  for (int q = 0; q < 4; q++) {
    const int slot = q * 256 + tid;           // 0..1023 = sm*64 + lane
    const int lane = slot & 63, sm = slot >> 6;
    const int s = sm >> 1, mt = sm & 1;
    const int hi = lane >> 5, ln = lane & 31;
    const int n = 32 * mt + ln;
    ushort8 t;
#pragma unroll
    for (int j = 0; j < 8; j++) {
      const int k2 = 16 * s + 8 * hi + j;
      float v;
      if (dir == 0) {
        v = S[k2 * 64 + n] - ((n == (k2 >> 1)) ? 1.f : 0.f);
      } else {
        const int r = k2 >> 1, p = k2 & 1;
        v = S[n * 128 + p * 64 + r] - ((n == r) ? 1.f : 0.f);
      }
      const unsigned uu = __builtin_bit_cast(unsigned, v);
      t[j] = (unsigned short)((uu + 0x7FFFu + ((uu >> 16) & 1u)) >> 16);  // RNE
    }
    *(ushort8*)&dst[(size_t)slot * 8] = t;
  }
}

// ---- per-site core + pipelined staging, macro for static reg naming ----
// FC: frag regs for site I (vf4[16]); FN: array to fill with site I+1 frags
// CS/SN: cos/sin for site I (overwritten with site I+2's after use)
// XR: x value for site I+2 (loaded last window); XW: receives x(I+3)
#define BODY(I, FC, FN, CS, SN, XR, XW, LAST)                                  \
  {                                                                            \
    const float keff = CS + SN;                                                \
    short8 e2[8];                                                              \
    _Pragma("unroll")                                                          \
    for (int s = 0; s < 8; s++) {                                              \
      int pk[4];                                                               \
      _Pragma("unroll")                                                        \
      for (int t = 0; t < 4; t++) {                                            \
        const float uv = u[s >> 2][(s & 3) * 4 + t];                           \
        const float f0 = uv * CS, f1 = uv * SN;                                \
        int p;                                                                 \
        asm("v_cvt_pk_bf16_f32 %0, %1, %2" : "=v"(p) : "v"(f0), "v"(f1));      \
        pk[t] = p;                                                             \
      }                                                                        \
      short8 e;                                                                \
      _Pragma("unroll")                                                        \
      for (int t = 0; t < 4; t++) {                                            \
        e[2 * t] = (short)(pk[t] & 0xFFFF);                                    \
        e[2 * t + 1] = (short)((unsigned)pk[t] >> 16);                         \
      }                                                                        \
      e2[s] = e;                                                               \
    }                                                                          \
    f32x16 a0a = {}, a0b = {}, a1a = {}, a1b = {};                             \
    _Pragma("unroll")                                                          \
    for (int s = 0; s < 4; s++) {                                              \
      a0a = __builtin_amdgcn_mfma_f32_32x32x16_bf16(                           \
          __builtin_bit_cast(short8, FC[2 * s]), e2[s], a0a, 0, 0, 0);         \
      a1a = __builtin_amdgcn_mfma_f32_32x32x16_bf16(                           \
          __builtin_bit_cast(short8, FC[2 * s + 1]), e2[s], a1a, 0, 0, 0);     \
    }                                                                          \
    _Pragma("unroll")                                                          \
    for (int s = 4; s < 8; s++) {                                              \
      a0b = __builtin_amdgcn_mfma_f32_32x32x16_bf16(                           \
          __builtin_bit_cast(short8, FC[2 * s]), e2[s], a0b, 0, 0, 0);         \
      a1b = __builtin_amdgcn_mfma_f32_32x32x16_bf16(                           \
          __builtin_bit_cast(short8, FC[2 * s + 1]), e2[s], a1b, 0, 0, 0);     \
    }                                                                          \
    if (!(LAST)) {                                                             \
      const int nsite = ((I) + 3 < NS) ? ((I) + 3) : (NS - 1);                 \
      XW = xrow[dir ? (1022 - nsite) : (1 + nsite)];                           \
      const float* Wn = W + (size_t)nsite * 4096;                              \
      float* dstb = &wf[((I) + 3) & 3][0];                                     \
      _Pragma("unroll")                                                        \
      for (int q = 0; q < 16; q++)                                             \
        gld_lds16(Wn + (q * 64 + lane) * 4, dstb + (q * 64 + lane) * 4);       \
      asm volatile("s_waitcnt vmcnt(33)" ::: "memory");                        \
      const float* rb = &wf[((I) + 1) & 3][0];                                 \
      _Pragma("unroll")                                                        \
      for (int q = 0; q < 16; q++)                                             \
        FN[q] = *(const vf4*)&rb[(q * 64 + lane) * 4];                         \
      const float ang = PI_2 * XR;                                             \
      CS = __cosf(ang);                                                        \
      SN = __sinf(ang);                                                        \
    }                                                                          \
    _Pragma("unroll")                                                          \
    for (int r = 0; r < 16; r++) {                                             \
      u[0][r] = keff * u[0][r] + (a0a[r] + a0b[r]);                            \
      u[1][r] = keff * u[1][r] + (a1a[r] + a1b[r]);                            \
    }                                                                          \
    if (((I) & 7) == 7) { /* exact pow2 rescale, keeps fp32 in range */        \
      float nss = 0.f;                                                         \
      _Pragma("unroll")                                                        \
      for (int r = 0; r < 16; r++)                                             \
        nss += u[0][r] * u[0][r] + u[1][r] * u[1][r];                          \
      nss += __shfl_xor(nss, 32);                                              \
      const int eb = (__float_as_int(nss) >> 23) & 0xFF;                       \
      const float alpha = __int_as_float((127 - ((eb - 127) >> 1)) << 23);     \
      _Pragma("unroll")                                                        \
      for (int r = 0; r < 16; r++) { u[0][r] *= alpha; u[1][r] *= alpha; }     \
    }                                                                          \
  }

// ---- sweep: 1 wave = 32 batch chains; deferred norm; 3-deep prefetch ----
__global__ __launch_bounds__(64, 1) void sweep(const float* __restrict__ x,
                                               const float* __restrict__ left0,
                                               const float* __restrict__ right_last,
                                               const unsigned short* __restrict__ Wl,
                                               const unsigned short* __restrict__ Wr,
                                               float* __restrict__ envL,
                                               float* __restrict__ envR) {
  __shared__ float wf[4][4096];           // 4 x 16KB site-frag buffers
  const int bid = blockIdx.x;
  const int dir = bid >> 7;
  const int lane = threadIdx.x;
  const int hi = lane >> 5, ln = lane & 31;
  const int b = (bid & 127) * 32 + ln;
  const float* xrow = x + (size_t)b * LL;

  const float* W = (const float*)(dir ? Wr : Wl);

  // init env from boundary tensor (fp32, exact normalize)
  float u[2][16];
  {
    const float x0 = xrow[dir ? (LL - 1) : 0];
    const float ang = PI_2 * x0;
    const float sn = __sinf(ang), cs = __cosf(ang);
#pragma unroll
    for (int mt = 0; mt < 2; mt++)
#pragma unroll
      for (int r = 0; r < 16; r++) {
        const int n = 32 * mt + 8 * (r >> 2) + 4 * hi + (r & 3);
        const float w0 = dir ? right_last[n * 2] : left0[n];
        const float w1 = dir ? right_last[n * 2 + 1] : left0[64 + n];
        u[mt][r] = cs * w0 + sn * w1;
      }
    float ss = 0.f;
#pragma unroll
    for (int mt = 0; mt < 2; mt++)
#pragma unroll
      for (int r = 0; r < 16; r++) ss += u[mt][r] * u[mt][r];
    ss += __shfl_xor(ss, 32);
    const float a0 = 1.f / (sqrtf(ss) + 1e-8f);
#pragma unroll
    for (int mt = 0; mt < 2; mt++)
#pragma unroll
      for (int r = 0; r < 16; r++) u[mt][r] *= a0;
  }

  // ---- prologue: x(0..2) + stage sites 0..2, then frag(0) + sincos(0,1) ----
  float xv0 = xrow[dir ? 1022 : 1];
  float xv1 = xrow[dir ? 1021 : 2];
  float xvB = xrow[dir ? 1020 : 3];
  float xvA;
#pragma unroll
  for (int q = 0; q < 16; q++)
    gld_lds16(W + (q * 64 + lane) * 4, &wf[0][(q * 64 + lane) * 4]);
#pragma unroll
  for (int q = 0; q < 16; q++)
    gld_lds16(W + (size_t)1 * 4096 + (q * 64 + lane) * 4, &wf[1][(q * 64 + lane) * 4]);
#pragma unroll
  for (int q = 0; q < 16; q++)
    gld_lds16(W + (size_t)2 * 4096 + (q * 64 + lane) * 4, &wf[2][(q * 64 + lane) * 4]);
  asm volatile("s_waitcnt vmcnt(32)" ::: "memory");

  vf4 fA[16], fB[16];
#pragma unroll
  for (int q = 0; q < 16; q++)
    fA[q] = *(const vf4*)&wf[0][(q * 64 + lane) * 4];

  float csE, snE, csO, snO;
  { const float ang = PI_2 * xv0; csE = __cosf(ang); snE = __sinf(ang); }
  { const float ang = PI_2 * xv1; csO = __cosf(ang); snO = __sinf(ang); }

  // ---- main loop: sites 0..509, unrolled x2 for static reg roles ----
  for (int i = 0; i < NS - 1; i += 2) {
    BODY(i, fA, fB, csE, snE, xvB, xvA, 0)
    BODY(i + 1, fB, fA, csO, snO, xvA, xvB, 0)
  }
  // site 510: frags in fA, cs/sn in csE/snE
  BODY(NS - 1, fA, fB, csE, snE, xvB, xvA, 1)

  // final exact normalize + store
  float nss = 0.f;
#pragma unroll
  for (int mt = 0; mt < 2; mt++)
#pragma unroll
    for (int r = 0; r < 16; r++) nss += u[mt][r] * u[mt][r];
  nss += __shfl_xor(nss, 32);
  const float alpha = 1.f / (sqrtf(nss) + 1e-8f);

  float* eo = (dir ? envR : envL) + (size_t)b * 64;
#pragma unroll
  for (int mt = 0; mt < 2; mt++)
#pragma unroll
    for (int g = 0; g < 4; g++) {
      vf4 v;
#pragma unroll
      for (int q = 0; q < 4; q++) v[q] = u[mt][g * 4 + q] * alpha;
      *(vf4*)&eo[32 * mt + 8 * g + 4 * hi] = v;
    }
  asm volatile("s_waitcnt vmcnt(0)" ::: "memory");  // drain tail prefetches
}

// ---- center contraction (unchanged, fp32) ----
__global__ __launch_bounds__(256) void centerk(const float* __restrict__ envL,
                                               const float* __restrict__ envR,
                                               const float* __restrict__ center,
                                               float* __restrict__ Pp) {
  __shared__ float Cs[2][SITE_F];
  __shared__ float LT[64 * 36];
  __shared__ float RT[64 * 36];
  const int bbase = blockIdx.x * 32;
  const int half = blockIdx.y;
  const int tid = threadIdx.x;
  const int och = tid & 31, bch = tid >> 5;
  const int o0 = och * 4, b0 = bch * 4;
#pragma unroll
  for (int m = 0; m < 8; m++) {
    const int idx = m * 256 + tid;
    const int b = idx >> 6, l = idx & 63;
    LT[l * 36 + b] = envL[(bbase + b) * 64 + l];
    RT[l * 36 + b] = envR[(bbase + b) * 64 + l];
  }
  stage32k_256(Cs[0], center + (half * 32) * SITE_F, tid);
  float acc[4][4] = {};
  for (int lh = 0; lh < 32; lh++) {
    __syncthreads();
    const int buf = lh & 1;
    if (lh + 1 < 32) stage32k_256(Cs[buf ^ 1], center + (half * 32 + lh + 1) * SITE_F, tid);
    const vf4 lv = *(const vf4*)&LT[(half * 32 + lh) * 36 + b0];
    const float* C = Cs[buf];
#pragma unroll
    for (int r = 0; r < 64; r++) {
      const vf4 rv = *(const vf4*)&RT[r * 36 + b0];
      const vf4 cv = *(const vf4*)&C[r * 128 + o0];
#pragma unroll
      for (int i2 = 0; i2 < 4; i2++) {
        const float w = lv[i2] * rv[i2];
        acc[i2][0] += w * cv[0];
        acc[i2][1] += w * cv[1];
        acc[i2][2] += w * cv[2];
        acc[i2][3] += w * cv[3];
      }
    }
  }
#pragma unroll
  for (int i2 = 0; i2 < 4; i2++) {
    vf4 v; v[0] = acc[i2][0]; v[1] = acc[i2][1]; v[2] = acc[i2][2]; v[3] = acc[i2][3];
    *(vf4*)&Pp[(size_t)half * BBATCH * 128 + (size_t)(bbase + b0 + i2) * 128 + o0] = v;
  }
}

// ---- combine halves + row-normalize ----
__global__ __launch_bounds__(256) void combinek(const float* __restrict__ P,
                                                float* __restrict__ out) {
  const float* P0 = P;
  const float* P1 = P + (size_t)BBATCH * 128;
  const int row = blockIdx.x * 8 + (threadIdx.x >> 5);
  const int o0 = (threadIdx.x & 31) * 4;
  vf4 v = *(const vf4*)&P0[(size_t)row * 128 + o0];
  const vf4 v1 = *(const vf4*)&P1[(size_t)row * 128 + o0];
  v += v1;
  float ss = v[0] * v[0] + v[1] * v[1] + v[2] * v[2] + v[3] * v[3];
#pragma unroll
  for (int m = 1; m < 32; m <<= 1) ss += __shfl_xor(ss, m);
  const float inv = 1.f / fmaxf(sqrtf(ss), 1e-12f);
  v *= inv;
  *(vf4*)&out[(size_t)row * 128 + o0] = v;
}

extern "C" void kernel_launch(void* const* d_in, const int* in_sizes, int n_in,
                              void* d_out, int out_size, void* d_ws, size_t ws_size,
                              hipStream_t stream) {
  const float* x = (const float*)d_in[0];
  const float* left0 = (const float*)d_in[1];
  const float* left_rest = (const float*)d_in[2];
  const float* center = (const float*)d_in[3];
  const float* right_rest = (const float*)d_in[4];
  const float* right_last = (const float*)d_in[5];
  float* out = (float*)d_out;

  char* wsb = (char*)d_ws;
  unsigned short* Wl = (unsigned short*)wsb;                       // 8.37 MB
  unsigned short* Wr = Wl + (size_t)NS * SITE_F;                   // 8.37 MB
  float* envL = (float*)(Wr + (size_t)NS * SITE_F);                // 1 MB
  float* envR = envL + (size_t)BBATCH * 64;                        // 1 MB
  float* Pp = envR + (size_t)BBATCH * 64;                          // 4.2 MB

  hipLaunchKernelGGL(prep, dim3(NS, 2), dim3(256), 0, stream,
                     left_rest, right_rest, Wl, Wr);
  hipLaunchKernelGGL(sweep, dim3(256), dim3(64), 0, stream,
                     x, left0, right_last, Wl, Wr, envL, envR);
  hipLaunchKernelGGL(centerk, dim3(BBATCH / 32, 2), dim3(256), 0, stream,
                     envL, envR, center, Pp);
  hipLaunchKernelGGL(combinek, dim3(BBATCH / 8), dim3(256), 0, stream, Pp, out);
}